// Round 15
// baseline (89.186 us; speedup 1.0000x reference)
//
#include <hip/hip_runtime.h>

#define TOKENS 16384
#define EMB 4096
#define NEXP 64
#define KSP 4
#define MK 128               // macro k-span (4 groups x 32)
#define NM (EMB / MK)        // 32 macro-steps
#define BKG 32               // per-group k per macro

typedef __attribute__((ext_vector_type(8))) short short8;
typedef __attribute__((ext_vector_type(4))) float f32x4;
typedef __attribute__((ext_vector_type(4))) unsigned short ush4;

#define WP_USHORTS (3 * NEXP * EMB)   // 1.5 MB bf16 W-planes (L2-resident)
#define WP_FLOATS  (WP_USHORTS / 2)

// async global->LDS, 16B/lane; dest = wave-uniform base + lane*16
__device__ __forceinline__ void gl_lds16(const void* g, void* lds) {
    __builtin_amdgcn_global_load_lds(
        (const __attribute__((address_space(1))) void*)g,
        (__attribute__((address_space(3))) void*)lds, 16, 0, 0);
}

// fp32 -> 3x bf16, scalar (W prep): hi RN, mid/lo trunc (R7-R14 exact).
__device__ __forceinline__ void split3(float x, unsigned short& h,
                                       unsigned short& m, unsigned short& l) {
    unsigned u = __float_as_uint(x);
    unsigned r = u + 0x7FFFu + ((u >> 16) & 1u);
    float hF = __uint_as_float(r & 0xFFFF0000u);
    h = (unsigned short)(r >> 16);
    float r1 = x - hF;
    unsigned u1 = __float_as_uint(r1);
    float mF = __uint_as_float(u1 & 0xFFFF0000u);
    m = (unsigned short)(u1 >> 16);
    float r2 = r1 - mF;
    l = (unsigned short)(__float_as_uint(r2) >> 16);
}

// pair-wise split -> packed bf16 words (identical planes; v_perm packing).
__device__ __forceinline__ void split3_pair(float x0, float x1,
        unsigned& hw, unsigned& mw, unsigned& lw) {
    unsigned u0 = __float_as_uint(x0), u1 = __float_as_uint(x1);
    unsigned r0 = u0 + 0x7FFFu + ((u0 >> 16) & 1u);
    unsigned r1 = u1 + 0x7FFFu + ((u1 >> 16) & 1u);
    hw = __builtin_amdgcn_perm(r1, r0, 0x07060302u);
    float s0 = x0 - __uint_as_float(r0 & 0xFFFF0000u);
    float s1 = x1 - __uint_as_float(r1 & 0xFFFF0000u);
    unsigned v0 = __float_as_uint(s0), v1 = __float_as_uint(s1);
    mw = __builtin_amdgcn_perm(v1, v0, 0x07060302u);
    float t0 = s0 - __uint_as_float(v0 & 0xFFFF0000u);
    float t1 = s1 - __uint_as_float(v1 & 0xFFFF0000u);
    lw = __builtin_amdgcn_perm(__float_as_uint(t1), __float_as_uint(t0), 0x07060302u);
}

// prep: split W into 3 bf16 planes Wp[plane][e][k] (flat row r = plane*64+e)
__global__ __launch_bounds__(256) void split_w(const float* __restrict__ W,
                                               unsigned short* __restrict__ Wp) {
    const int i = (blockIdx.x * 256 + threadIdx.x) * 4;
    const float4 v = *reinterpret_cast<const float4*>(W + i);
    ush4 h, m, l;
#pragma unroll
    for (int e = 0; e < 4; ++e) {
        unsigned short he, me, le;
        split3(reinterpret_cast<const float*>(&v)[e], he, me, le);
        h[e] = he; m[e] = me; l[e] = le;
    }
    *reinterpret_cast<ush4*>(Wp + i) = h;
    *reinterpret_cast<ush4*>(Wp + NEXP * EMB + i) = m;
    *reinterpret_cast<ush4*>(Wp + 2 * NEXP * EMB + i) = l;
}

// Fused router, R15: INTERLEAVED k-split + contiguous A staging.
// R11-R14 pinned at main ~65-70us across 4 schedules while x streamed at
// only ~3.9 TB/s effective; hypothesis: 128-B-per-row HBM visits (BK*4B,
// 16KB row stride) are the limiter. Fix: group g takes k in
// [m*128+g*32,+32) per macro m, so the BLOCK consumes 128 consecutive k
// -> A staged as x[64tok][128k] units, each wave-instr reading 2 rows x
// 512 B CONTIGUOUS. Staging threads split3 to bf16 planes and ds_write
// XOR-swizzled A-planes (48 KB, single-buf); compute waves ds_read_b128
// frags (swz: slot^(tok&7), 8 addrs/quad = floor). B = R14 verbatim
// (gl_lds dbuf per group). 2 barriers per macro (was 4). Numerics:
// identical split-3/6-term/segregated-acc; only k-partition per group
// changes (idx exact, probs ~1e-3-level diffs possible).
__global__ __launch_bounds__(512, 1) void router_fused(
    const float* __restrict__ x, const unsigned short* __restrict__ Wp,
    const float* __restrict__ b, float* __restrict__ out)
{
    __shared__ __align__(16) unsigned short sA[3 * 64 * MK];      // 48 KB
    __shared__ __align__(16) unsigned short sB[KSP][2][192][BKG]; // 96 KB

    const int t  = threadIdx.x;
    const int w  = t >> 6;
    const int l  = t & 63;
    const int g  = w >> 1;     // k-subchunk group 0..3
    const int h  = w & 1;      // token half 0/1
    const int lr = l & 15;     // A token-row / B expert-col
    const int lo = l >> 4;     // k-octet selector within group slice
    const int tokB = blockIdx.x * 64;

    // A staging source: piece j -> row 16j+(t>>5), k-piece (t&31)*4 floats.
    // Wave-level: 2 rows x 512 B contiguous per load instruction.
    const float* axj[4];
#pragma unroll
    for (int j = 0; j < 4; ++j)
        axj[j] = x + (size_t)(tokB + 16 * j + (t >> 5)) * EMB + (t & 31) * 4;

    // A-plane write indexing (u32 units). slot = octet (t&31)>>1, swizzled
    // by tok&7 = (t>>5)&7 (16j drops out mod 8); half = t&1.
    unsigned* sAu = reinterpret_cast<unsigned*>(sA);
    const int swzW = ((t & 31) >> 1) ^ ((t >> 5) & 7);
    const int wbase0 = (t >> 5) * 64 + swzW * 4 + (t & 1) * 2;

    // B staging (R14): wave (g,h), p=0..5 -> sB[g] rows 16(6h+p)..+15
    const unsigned short* gb[6];
#pragma unroll
    for (int p = 0; p < 6; ++p)
        gb[p] = Wp + (size_t)(16 * (6 * h + p) + (l >> 2)) * EMB
              + g * BKG + 8 * (l & 3);

    f32x4 accH[2][4], accL[2][4];
#pragma unroll
    for (int ti = 0; ti < 2; ++ti)
#pragma unroll
        for (int et = 0; et < 4; ++et) {
            accH[ti][et] = (f32x4){0.f, 0.f, 0.f, 0.f};
            accL[ti][et] = (f32x4){0.f, 0.f, 0.f, 0.f};
        }

    // prologue: issue B(0) + A(0)
#pragma unroll
    for (int p = 0; p < 6; ++p)
        gl_lds16(gb[p], &sB[g][0][16 * (6 * h + p)][0]);
    float4 ar[4];
#pragma unroll
    for (int j = 0; j < 4; ++j)
        ar[j] = *reinterpret_cast<const float4*>(axj[j]);

#pragma unroll 1
    for (int m = 0; m < NM; ++m) {
        const int buf = m & 1;
        // A(m) regs + B(m) gl_lds landed (issued last macro, ~1 macro cover)
        asm volatile("s_waitcnt vmcnt(0)" ::: "memory");
        __builtin_amdgcn_s_barrier();   // planes(m-1) readers done; B(m) ok
        __builtin_amdgcn_sched_barrier(0);

        if (m + 1 < NM) {               // issue B(m+1)
#pragma unroll
            for (int p = 0; p < 6; ++p)
                gl_lds16(gb[p] + (m + 1) * MK,
                         &sB[g][buf ^ 1][16 * (6 * h + p)][0]);
        }
        // split A(m) -> swizzled bf16 planes (one b64 per plane per piece)
#pragma unroll
        for (int j = 0; j < 4; ++j) {
            const float4 f = ar[j];
            unsigned hw0, mw0, lw0, hw1, mw1, lw1;
            split3_pair(f.x, f.y, hw0, mw0, lw0);
            split3_pair(f.z, f.w, hw1, mw1, lw1);
            const int rb = 16 * j * 64 + wbase0;
            *reinterpret_cast<unsigned long long*>(sAu + rb)
                = ((unsigned long long)hw1 << 32) | hw0;
            *reinterpret_cast<unsigned long long*>(sAu + 4096 + rb)
                = ((unsigned long long)mw1 << 32) | mw0;
            *reinterpret_cast<unsigned long long*>(sAu + 8192 + rb)
                = ((unsigned long long)lw1 << 32) | lw0;
        }
        if (m + 1 < NM) {               // reload A(m+1) into freed regs
#pragma unroll
            for (int j = 0; j < 4; ++j)
                ar[j] = *reinterpret_cast<const float4*>(axj[j] + (m + 1) * MK);
        }
        asm volatile("s_waitcnt lgkmcnt(0)" ::: "memory");
        __builtin_amdgcn_s_barrier();   // planes(m) visible to all waves
        __builtin_amdgcn_sched_barrier(0);

        // A frags from planes: octet o = g*4+lo, swz with tok&7 (= lr&7)
        short8 fr[2][3];
#pragma unroll
        for (int ti = 0; ti < 2; ++ti) {
            const int tok = h * 32 + ti * 16 + lr;
            const int o   = (g * 4 + lo) ^ (lr & 7);
            const unsigned short* pa = sA + tok * MK + o * 8;
            fr[ti][0] = *reinterpret_cast<const short8*>(pa);
            fr[ti][1] = *reinterpret_cast<const short8*>(pa + 8192);
            fr[ti][2] = *reinterpret_cast<const short8*>(pa + 16384);
        }
#pragma unroll
        for (int et = 0; et < 4; ++et) {
            const unsigned short* bp = &sB[g][buf][et * 16 + lr][lo * 8];
            const short8 bH = *reinterpret_cast<const short8*>(bp);
            const short8 bM = *reinterpret_cast<const short8*>(bp + 64 * BKG);
            const short8 bL = *reinterpret_cast<const short8*>(bp + 128 * BKG);
#pragma unroll
            for (int ti = 0; ti < 2; ++ti) {
                accH[ti][et] = __builtin_amdgcn_mfma_f32_16x16x32_bf16(fr[ti][0], bH, accH[ti][et], 0, 0, 0);
                accL[ti][et] = __builtin_amdgcn_mfma_f32_16x16x32_bf16(fr[ti][0], bM, accL[ti][et], 0, 0, 0);
                accL[ti][et] = __builtin_amdgcn_mfma_f32_16x16x32_bf16(fr[ti][1], bH, accL[ti][et], 0, 0, 0);
                accL[ti][et] = __builtin_amdgcn_mfma_f32_16x16x32_bf16(fr[ti][1], bM, accL[ti][et], 0, 0, 0);
                accL[ti][et] = __builtin_amdgcn_mfma_f32_16x16x32_bf16(fr[ti][0], bL, accL[ti][et], 0, 0, 0);
                accL[ti][et] = __builtin_amdgcn_mfma_f32_16x16x32_bf16(fr[ti][2], bH, accL[ti][et], 0, 0, 0);
            }
        }
    }

    // ---- fused epilogue (R14-proven): combine + top-2 + softmax ----
    __syncthreads();
    float* logits = reinterpret_cast<float*>(&sB[0][0][0][0]); // [4][64][65]
#pragma unroll
    for (int ti = 0; ti < 2; ++ti)
#pragma unroll
        for (int et = 0; et < 4; ++et)
#pragma unroll
            for (int j = 0; j < 4; ++j) {
                const int ltok = h * 32 + ti * 16 + lo * 4 + j;
                logits[(g * 64 + ltok) * 65 + et * 16 + lr]
                    = accH[ti][et][j] + accL[ti][et][j];
            }
    __syncthreads();

    double* sv = reinterpret_cast<double*>(logits + KSP * 64 * 65); // [64][8][2]
    int*    si = reinterpret_cast<int*>(sv + 64 * 8 * 2);

    const int tok  = t >> 3;    // 0..63
    const int part = t & 7;     // 8 experts each
    double v[8];
#pragma unroll
    for (int j = 0; j < 8; ++j) v[j] = 0.0;
#pragma unroll
    for (int gg = 0; gg < KSP; ++gg)
#pragma unroll
        for (int j = 0; j < 8; ++j)
            v[j] += (double)logits[(gg * 64 + tok) * 65 + part * 8 + j];
#pragma unroll
    for (int j = 0; j < 8; ++j) v[j] += (double)b[part * 8 + j];

    double v1 = -1e300, v2 = -1e300; int i1 = 0, i2 = 0;
#pragma unroll
    for (int j = 0; j < 8; ++j) {        // ascending: ties keep lowest idx
        const int e = part * 8 + j;
        if (v[j] > v1)      { v2 = v1; i2 = i1; v1 = v[j]; i1 = e; }
        else if (v[j] > v2) { v2 = v[j]; i2 = e; }
    }
    sv[(tok * 8 + part) * 2 + 0] = v1;
    sv[(tok * 8 + part) * 2 + 1] = v2;
    si[(tok * 8 + part) * 2 + 0] = i1;
    si[(tok * 8 + part) * 2 + 1] = i2;
    __syncthreads();

    if (part == 0) {
        double m1 = -1e300, m2 = -1e300; int j1 = 0, j2 = 0;
#pragma unroll
        for (int p = 0; p < 8; ++p)      // ascending parts: lowest idx on tie
#pragma unroll
            for (int r = 0; r < 2; ++r) {
                const double vv = sv[(tok * 8 + p) * 2 + r];
                const int    ii = si[(tok * 8 + p) * 2 + r];
                if (vv > m1)      { m2 = m1; j2 = j1; m1 = vv; j1 = ii; }
                else if (vv > m2) { m2 = vv; j2 = ii; }
            }
        const float e2  = expf((float)(m2 - m1));   // <= 1
        const float inv = 1.0f / (1.0f + e2);
        const int gt = tokB + tok;
        out[2 * gt]     = (float)j1;
        out[2 * gt + 1] = (float)j2;
        out[2 * TOKENS + 2 * gt]     = inv;
        out[2 * TOKENS + 2 * gt + 1] = e2 * inv;
    }
}

extern "C" void kernel_launch(void* const* d_in, const int* in_sizes, int n_in,
                              void* d_out, int out_size, void* d_ws, size_t ws_size,
                              hipStream_t stream) {
    const float* x = (const float*)d_in[0];
    const float* W = (const float*)d_in[1];
    const float* b = (const float*)d_in[2];
    float* out = (float*)d_out;
    unsigned short* Wp = (unsigned short*)d_ws;   // 1.5 MB, always fits

    split_w<<<dim3(NEXP * EMB / 1024), dim3(256), 0, stream>>>(W, Wp);
    router_fused<<<dim3(TOKENS / 64), dim3(512), 0, stream>>>(x, Wp, b, out);
}

// Round 16
// 85.647 us; speedup vs baseline: 1.0413x; 1.0413x over previous
//
#include <hip/hip_runtime.h>

#define TOKENS 16384
#define EMB 4096
#define NEXP 64
#define BK 32
#define KSP 4
#define KPER (EMB / KSP)      // 1024
#define NCH (KPER / BK)       // 32 chunks per group
#define NMM (NCH / 2)         // 16 macros of 2 chunks

typedef __attribute__((ext_vector_type(8))) short short8;
typedef __attribute__((ext_vector_type(4))) float f32x4;
typedef __attribute__((ext_vector_type(4))) unsigned short ush4;

#define WP_USHORTS (3 * NEXP * EMB)   // 1.5 MB bf16 W-planes (L2-resident)
#define WP_FLOATS  (WP_USHORTS / 2)

// async global->LDS, 16B/lane; dest = wave-uniform base + lane*16
__device__ __forceinline__ void gl_lds16(const void* g, void* lds) {
    __builtin_amdgcn_global_load_lds(
        (const __attribute__((address_space(1))) void*)g,
        (__attribute__((address_space(3))) void*)lds, 16, 0, 0);
}

// fp32 -> 3x bf16, scalar (W prep): hi RN, mid/lo trunc (R7-R14 exact).
__device__ __forceinline__ void split3(float x, unsigned short& h,
                                       unsigned short& m, unsigned short& l) {
    unsigned u = __float_as_uint(x);
    unsigned r = u + 0x7FFFu + ((u >> 16) & 1u);
    float hF = __uint_as_float(r & 0xFFFF0000u);
    h = (unsigned short)(r >> 16);
    float r1 = x - hF;
    unsigned u1 = __float_as_uint(r1);
    float mF = __uint_as_float(u1 & 0xFFFF0000u);
    m = (unsigned short)(u1 >> 16);
    float r2 = r1 - mF;
    l = (unsigned short)(__float_as_uint(r2) >> 16);
}

// pair-wise split -> packed bf16 words (identical planes; v_perm packing).
__device__ __forceinline__ void split3_pair(float x0, float x1,
        unsigned& hw, unsigned& mw, unsigned& lw) {
    unsigned u0 = __float_as_uint(x0), u1 = __float_as_uint(x1);
    unsigned r0 = u0 + 0x7FFFu + ((u0 >> 16) & 1u);
    unsigned r1 = u1 + 0x7FFFu + ((u1 >> 16) & 1u);
    hw = __builtin_amdgcn_perm(r1, r0, 0x07060302u);
    float s0 = x0 - __uint_as_float(r0 & 0xFFFF0000u);
    float s1 = x1 - __uint_as_float(r1 & 0xFFFF0000u);
    unsigned v0 = __float_as_uint(s0), v1 = __float_as_uint(s1);
    mw = __builtin_amdgcn_perm(v1, v0, 0x07060302u);
    float t0 = s0 - __uint_as_float(v0 & 0xFFFF0000u);
    float t1 = s1 - __uint_as_float(v1 & 0xFFFF0000u);
    lw = __builtin_amdgcn_perm(__float_as_uint(t1), __float_as_uint(t0), 0x07060302u);
}

// 8 floats (one lane's 32-k A slice) -> three short8 MFMA fragments
__device__ __forceinline__ void build_frags(const float4& a0, const float4& a1,
        short8& H, short8& M, short8& L) {
    union { short8 v; unsigned u[4]; } h_, m_, l_;
    split3_pair(a0.x, a0.y, h_.u[0], m_.u[0], l_.u[0]);
    split3_pair(a0.z, a0.w, h_.u[1], m_.u[1], l_.u[1]);
    split3_pair(a1.x, a1.y, h_.u[2], m_.u[2], l_.u[2]);
    split3_pair(a1.z, a1.w, h_.u[3], m_.u[3], l_.u[3]);
    H = h_.v; M = m_.v; L = l_.v;
}

// prep: split W into 3 bf16 planes Wp[plane][e][k] (flat row r = plane*64+e)
__global__ __launch_bounds__(256) void split_w(const float* __restrict__ W,
                                               unsigned short* __restrict__ Wp) {
    const int i = (blockIdx.x * 256 + threadIdx.x) * 4;
    const float4 v = *reinterpret_cast<const float4*>(W + i);
    ush4 h, m, l;
#pragma unroll
    for (int e = 0; e < 4; ++e) {
        unsigned short he, me, le;
        split3(reinterpret_cast<const float*>(&v)[e], he, me, le);
        h[e] = he; m[e] = me; l[e] = le;
    }
    *reinterpret_cast<ush4*>(Wp + i) = h;
    *reinterpret_cast<ush4*>(Wp + NEXP * EMB + i) = m;
    *reinterpret_cast<ush4*>(Wp + 2 * NEXP * EMB + i) = l;
}

// Fused router, R16 = R14 + macro-2 A batching. Per macro (2 chunks):
// A for BOTH chunks issued back-to-back (per token row: 256 B sequential
// within ~10 cyc, vs R14's two 128-B visits ~3000 cyc apart) and kept in
// flight a FULL macro (retired at next macro's first wait) -> HBM demand
// rate-matched (~10.7 B/cyc/CU) instead of per-chunk bursts. B triple-
// buffered (buf = chunk%3) so B(c1) issues before the first barrier
// without racing (prev readers of that buf are >=2 barriers back).
// FIFO per macro: enter [A(mm)8, B(c0)6];
//   s1 B(c1); s2 A(mm+1); s3 vmcnt(14) {retires A(mm),B(c0)}; s4 barrier;
//   s5 compute c0; s6 B(c0+2); s7 vmcnt(14) {retires B(c1), A stays};
//   s8 barrier; s9 compute c1. Last macro: vmcnt(6)/vmcnt(0).
// Every cross-wave LDS consume = own-wait -> barrier -> read.
// k-partition/numerics = R14 EXACTLY (absmax 0.0).
#define MFMA_BLOCK(BUFC, AH0, AM0, AL0, AH1, AM1, AL1)                          \
    _Pragma("unroll")                                                           \
    for (int et = 0; et < 4; ++et) {                                            \
        const unsigned short* bp = &sB[g][BUFC][et * 16 + lr][lo * 8];          \
        const short8 bH = *reinterpret_cast<const short8*>(bp);                 \
        const short8 bM = *reinterpret_cast<const short8*>(bp + 64 * BK);       \
        const short8 bL = *reinterpret_cast<const short8*>(bp + 128 * BK);      \
        accH[0][et] = __builtin_amdgcn_mfma_f32_16x16x32_bf16(AH0, bH, accH[0][et], 0, 0, 0); \
        accL[0][et] = __builtin_amdgcn_mfma_f32_16x16x32_bf16(AH0, bM, accL[0][et], 0, 0, 0); \
        accL[0][et] = __builtin_amdgcn_mfma_f32_16x16x32_bf16(AM0, bH, accL[0][et], 0, 0, 0); \
        accL[0][et] = __builtin_amdgcn_mfma_f32_16x16x32_bf16(AM0, bM, accL[0][et], 0, 0, 0); \
        accL[0][et] = __builtin_amdgcn_mfma_f32_16x16x32_bf16(AH0, bL, accL[0][et], 0, 0, 0); \
        accL[0][et] = __builtin_amdgcn_mfma_f32_16x16x32_bf16(AL0, bH, accL[0][et], 0, 0, 0); \
        accH[1][et] = __builtin_amdgcn_mfma_f32_16x16x32_bf16(AH1, bH, accH[1][et], 0, 0, 0); \
        accL[1][et] = __builtin_amdgcn_mfma_f32_16x16x32_bf16(AH1, bM, accL[1][et], 0, 0, 0); \
        accL[1][et] = __builtin_amdgcn_mfma_f32_16x16x32_bf16(AM1, bH, accL[1][et], 0, 0, 0); \
        accL[1][et] = __builtin_amdgcn_mfma_f32_16x16x32_bf16(AM1, bM, accL[1][et], 0, 0, 0); \
        accL[1][et] = __builtin_amdgcn_mfma_f32_16x16x32_bf16(AH1, bL, accL[1][et], 0, 0, 0); \
        accL[1][et] = __builtin_amdgcn_mfma_f32_16x16x32_bf16(AL1, bH, accL[1][et], 0, 0, 0); \
    }

#define ISSUE_B(CHUNK, BUF)                                                     \
    _Pragma("unroll")                                                           \
    for (int p = 0; p < 6; ++p)                                                 \
        gl_lds16(gb[p] + (CHUNK) * BK, &sB[g][BUF][16 * (6 * h + p)][0]);

// 8 loads; per token row 256 B issued sequentially (c0 then c1 pieces)
#define ISSUE_A(MACRO, ASET)                                                    \
    _Pragma("unroll")                                                           \
    for (int ti = 0; ti < 2; ++ti) {                                            \
        const float* ab_ = ax[ti] + 2 * (MACRO) * BK;                           \
        ASET[ti][0][0] = *reinterpret_cast<const float4*>(ab_);                 \
        ASET[ti][0][1] = *reinterpret_cast<const float4*>(ab_ + 4);             \
        ASET[ti][1][0] = *reinterpret_cast<const float4*>(ab_ + BK);            \
        ASET[ti][1][1] = *reinterpret_cast<const float4*>(ab_ + BK + 4);        \
    }

#define COMPUTE(ASET, CI, BUFC) do {                                            \
    short8 aH0, aM0, aL0, aH1, aM1, aL1;                                        \
    build_frags(ASET[0][CI][0], ASET[0][CI][1], aH0, aM0, aL0);                 \
    build_frags(ASET[1][CI][0], ASET[1][CI][1], aH1, aM1, aL1);                 \
    MFMA_BLOCK(BUFC, aH0, aM0, aL0, aH1, aM1, aL1)                              \
} while (0)

#define BODY(MM, ACUR, ANXT, BC0, BC1, BC2, ISLAST) do {                        \
    ISSUE_B(2 * (MM) + 1, BC1);                      /* s1 */                   \
    if (!(ISLAST)) { ISSUE_A((MM) + 1, ANXT); }      /* s2 */                   \
    __builtin_amdgcn_sched_barrier(0);                                          \
    if (ISLAST) asm volatile("s_waitcnt vmcnt(6)" ::: "memory");  /* s3 */      \
    else        asm volatile("s_waitcnt vmcnt(14)" ::: "memory");               \
    __builtin_amdgcn_s_barrier();                    /* s4 */                   \
    __builtin_amdgcn_sched_barrier(0);                                          \
    COMPUTE(ACUR, 0, BC0);                           /* s5 */                   \
    if (!(ISLAST)) { ISSUE_B(2 * (MM) + 2, BC2); }   /* s6 */                   \
    __builtin_amdgcn_sched_barrier(0);                                          \
    if (ISLAST) asm volatile("s_waitcnt vmcnt(0)" ::: "memory");  /* s7 */      \
    else        asm volatile("s_waitcnt vmcnt(14)" ::: "memory");               \
    __builtin_amdgcn_s_barrier();                    /* s8 */                   \
    __builtin_amdgcn_sched_barrier(0);                                          \
    COMPUTE(ACUR, 1, BC1);                           /* s9 */                   \
} while (0)

__global__ __launch_bounds__(512) void router_fused(
    const float* __restrict__ x, const unsigned short* __restrict__ Wp,
    const float* __restrict__ b, float* __restrict__ out)
{
    __shared__ unsigned short sB[KSP][3][192][BK];   // 144 KB -> 1 block/CU

    const int t  = threadIdx.x;
    const int w  = t >> 6;     // wave 0..7
    const int l  = t & 63;
    const int g  = w >> 1;     // k-split group 0..3
    const int h  = w & 1;      // token half 0/1
    const int lr = l & 15;     // A token-row / B expert-col
    const int lo = l >> 4;     // k-octet selector
    const int tokB = blockIdx.x * 64;
    const int tok0 = tokB + h * 32;
    const int kb   = g * KPER;

    const float* ax[2];
    ax[0] = x + (size_t)(tok0 + lr) * EMB + kb + lo * 8;
    ax[1] = ax[0] + (size_t)16 * EMB;

    const unsigned short* gb[6];
#pragma unroll
    for (int p = 0; p < 6; ++p)
        gb[p] = Wp + (size_t)(16 * (6 * h + p) + (l >> 2)) * EMB + kb + 8 * (l & 3);

    f32x4 accH[2][4], accL[2][4];
#pragma unroll
    for (int ti = 0; ti < 2; ++ti)
#pragma unroll
        for (int et = 0; et < 4; ++et) {
            accH[ti][et] = (f32x4){0.f, 0.f, 0.f, 0.f};
            accL[ti][et] = (f32x4){0.f, 0.f, 0.f, 0.f};
        }

    // prologue: invariant order A(0) then B(chunk0)  -> [A0_8, B0_6]
    float4 aA[2][2][2], aB[2][2][2];
    ISSUE_A(0, aA);
    __builtin_amdgcn_sched_barrier(0);
    ISSUE_B(0, 0);
    __builtin_amdgcn_sched_barrier(0);

    // macros 0..11 (buf pattern period 3, A-set parity 2 -> unroll 6)
#pragma unroll 1
    for (int mb = 0; mb < 12; mb += 6) {
        BODY(mb + 0, aA, aB, 0, 1, 2, false);
        BODY(mb + 1, aB, aA, 2, 0, 1, false);
        BODY(mb + 2, aA, aB, 1, 2, 0, false);
        BODY(mb + 3, aB, aA, 0, 1, 2, false);
        BODY(mb + 4, aA, aB, 2, 0, 1, false);
        BODY(mb + 5, aB, aA, 1, 2, 0, false);
    }
    BODY(12, aA, aB, 0, 1, 2, false);
    BODY(13, aB, aA, 2, 0, 1, false);
    BODY(14, aA, aB, 1, 2, 0, false);
    BODY(15, aB, aA, 0, 1, 2, true);

    // ---- fused epilogue (R14-proven verbatim) ----
    __syncthreads();
    float* logits = reinterpret_cast<float*>(&sB[0][0][0][0]); // [4][64][65]
#pragma unroll
    for (int ti = 0; ti < 2; ++ti)
#pragma unroll
        for (int et = 0; et < 4; ++et)
#pragma unroll
            for (int j = 0; j < 4; ++j) {
                const int ltok = h * 32 + ti * 16 + lo * 4 + j;
                logits[(g * 64 + ltok) * 65 + et * 16 + lr]
                    = accH[ti][et][j] + accL[ti][et][j];
            }
    __syncthreads();

    double* sv = reinterpret_cast<double*>(logits + KSP * 64 * 65); // [64][8][2]
    int*    si = reinterpret_cast<int*>(sv + 64 * 8 * 2);

    const int tok  = t >> 3;    // 0..63
    const int part = t & 7;     // 8 experts each
    double v[8];
#pragma unroll
    for (int j = 0; j < 8; ++j) v[j] = 0.0;
#pragma unroll
    for (int gg = 0; gg < KSP; ++gg)
#pragma unroll
        for (int j = 0; j < 8; ++j)
            v[j] += (double)logits[(gg * 64 + tok) * 65 + part * 8 + j];
#pragma unroll
    for (int j = 0; j < 8; ++j) v[j] += (double)b[part * 8 + j];

    double v1 = -1e300, v2 = -1e300; int i1 = 0, i2 = 0;
#pragma unroll
    for (int j = 0; j < 8; ++j) {        // ascending: ties keep lowest idx
        const int e = part * 8 + j;
        if (v[j] > v1)      { v2 = v1; i2 = i1; v1 = v[j]; i1 = e; }
        else if (v[j] > v2) { v2 = v[j]; i2 = e; }
    }
    sv[(tok * 8 + part) * 2 + 0] = v1;
    sv[(tok * 8 + part) * 2 + 1] = v2;
    si[(tok * 8 + part) * 2 + 0] = i1;
    si[(tok * 8 + part) * 2 + 1] = i2;
    __syncthreads();

    if (part == 0) {
        double m1 = -1e300, m2 = -1e300; int j1 = 0, j2 = 0;
#pragma unroll
        for (int p = 0; p < 8; ++p)      // ascending parts: lowest idx on tie
#pragma unroll
            for (int r = 0; r < 2; ++r) {
                const double vv = sv[(tok * 8 + p) * 2 + r];
                const int    ii = si[(tok * 8 + p) * 2 + r];
                if (vv > m1)      { m2 = m1; j2 = j1; m1 = vv; j1 = ii; }
                else if (vv > m2) { m2 = vv; j2 = ii; }
            }
        const float e2  = expf((float)(m2 - m1));   // <= 1
        const float inv = 1.0f / (1.0f + e2);
        const int gt = tokB + tok;
        out[2 * gt]     = (float)j1;
        out[2 * gt + 1] = (float)j2;
        out[2 * TOKENS + 2 * gt]     = inv;
        out[2 * TOKENS + 2 * gt + 1] = e2 * inv;
    }
}

extern "C" void kernel_launch(void* const* d_in, const int* in_sizes, int n_in,
                              void* d_out, int out_size, void* d_ws, size_t ws_size,
                              hipStream_t stream) {
    const float* x = (const float*)d_in[0];
    const float* W = (const float*)d_in[1];
    const float* b = (const float*)d_in[2];
    float* out = (float*)d_out;
    unsigned short* Wp = (unsigned short*)d_ws;   // 1.5 MB, always fits

    split_w<<<dim3(NEXP * EMB / 1024), dim3(256), 0, stream>>>(W, Wp);
    router_fused<<<dim3(TOKENS / 64), dim3(512), 0, stream>>>(x, Wp, b, out);
}